// Round 8
// baseline (410.793 us; speedup 1.0000x reference)
//
#include <hip/hip_runtime.h>
#include <hip/hip_bf16.h>
#include <math.h>

// B=2, T=4096, DIM=1024, H=16, D=64. fp32 in/out; bf16 MFMA internally.
// out = softmax((RoPE(xWq^T) RoPE(xWk^T)^T)/8) (xWv^T) Wo^T
// Round 17 (GEMM: 128x256 tile, 64x128 per wave):
//  - the 64x64-per-wave structure is LDS-read-BW-bound (8 b128 reads per
//    16 MFMA = 512 cyc/CU/step vs 155 cyc MFMA -> ~30% MfmaUtil ceiling,
//    matches m97/m98). 64x128 per wave: 12 reads per 32 MFMA (1.33x less
//    LDS BW per FLOP), half the blocks (operand re-fetch halves), half
//    the barriers per MFMA.
//  - 3-buffer ring kept; 6 loads/step -> vmcnt(6) steady, 6/0 tail.
//  - epilogues widened to 8 j-cols; RoPE pairs (j, j+2) still lane-local.
//  - attn / prep unchanged.

typedef __attribute__((ext_vector_type(8))) short short8;   // 8 x bf16
typedef __attribute__((ext_vector_type(4))) short short4v;  // 4 x bf16
typedef __attribute__((ext_vector_type(4))) float floatx4;  // MFMA acc

using bf16 = __hip_bfloat16;

static constexpr int T_ = 4096;
static constexpr int C_ = 1024;   // DIM
static constexpr int M_ = 8192;   // B*T
static constexpr float QSCALE = 0.125f * 1.44269504088896340736f; // 1/8*log2(e)

#if __has_builtin(__builtin_amdgcn_mfma_f32_16x16x16bf16_1k)
#define USE_K16 1
#else
#define USE_K16 0
#endif

#if __has_builtin(__builtin_amdgcn_exp2f)
#define EXP2 __builtin_amdgcn_exp2f
#else
#define EXP2 exp2f
#endif

__device__ __forceinline__ floatx4 mfma16(short8 a, short8 b, floatx4 c) {
    return __builtin_amdgcn_mfma_f32_16x16x32_bf16(a, b, c, 0, 0, 0);
}
#if USE_K16
__device__ __forceinline__ floatx4 mfma_k16(short4v a, short4v b, floatx4 c) {
    return __builtin_amdgcn_mfma_f32_16x16x16bf16_1k(a, b, c, 0, 0, 0);
}
#endif

__device__ __forceinline__ short8 ld8(const bf16* p) {
    return *reinterpret_cast<const short8*>(p);
}
__device__ __forceinline__ short4v ld4(const bf16* p) {
    return *reinterpret_cast<const short4v*>(p);
}
__device__ __forceinline__ void st8(bf16* p, short8 v) {
    *reinterpret_cast<short8*>(p) = v;
}
__device__ __forceinline__ unsigned short f2bf(float x) {
    bf16 h = __float2bfloat16(x);
    return reinterpret_cast<unsigned short&>(h);
}

// two fp32 -> packed bf16 pair (round-half-up; inputs positive finite).
// D[15:0]=bf16(a), D[31:16]=bf16(b). 2x v_add + v_perm_b32 (sel in SGPR):
// v_perm combined bytes: 0-3 = S1(=ua), 4-7 = S0(=ub); take {2,3,6,7}.
__device__ __forceinline__ int pack2bf(float a, float b, unsigned sel) {
    const unsigned ua = __float_as_uint(a) + 0x8000u;
    const unsigned ub = __float_as_uint(b) + 0x8000u;
    int r;
    asm("v_perm_b32 %0, %1, %2, %3" : "=v"(r) : "v"(ub), "v"(ua), "s"(sel));
    return r;
}
__device__ __forceinline__ short4v i2s4(int lo, int hi) {
    union { int2 i; short4v s; } u;
    u.i.x = lo; u.i.y = hi;
    return u.s;
}
__device__ __forceinline__ short8 i2s8(int a, int b, int c, int d) {
    union { int4 i; short8 s; } u;
    u.i.x = a; u.i.y = b; u.i.z = c; u.i.w = d;
    return u.s;
}

// async global->LDS, 16 B per lane (global_load_lds_dwordx4).
__device__ __forceinline__ void cp16(const bf16* g, bf16* l) {
    __builtin_amdgcn_global_load_lds(
        (const __attribute__((address_space(1))) void*)g,
        (__attribute__((address_space(3))) void*)l, 16, 0, 0);
}

// ---------------------------------------------------------------------------
// Fused prep: blocks [0,4096) cvt x; [4096,6144) cvt 4 weights;
// [6144,6656) rope cos/sin table. 256 thr, 8 fp32->bf16 per thread.
// ---------------------------------------------------------------------------
__global__ __launch_bounds__(256)
void prep_kernel(const float* __restrict__ x,
                 const float* __restrict__ wq, const float* __restrict__ wk,
                 const float* __restrict__ wv, const float* __restrict__ wo,
                 bf16* __restrict__ xb, bf16* __restrict__ wqb,
                 float2* __restrict__ CS) {
    const int blk = blockIdx.x;
    if (blk < 6144) {
        const float* in;
        bf16* out;
        int i;
        if (blk < 4096) {                 // x: 2^20 groups of 8
            i = blk * 256 + threadIdx.x;
            in = x; out = xb;
        } else {                          // weights: 4 segs of 2^17 groups
            i = (blk - 4096) * 256 + threadIdx.x;
            const int seg = i >> 17;
            const int off = i & 131071;
            in = (seg == 0) ? wq : (seg == 1) ? wk : (seg == 2) ? wv : wo;
            out = wqb + (size_t)i * 8 - (size_t)off * 8;  // seg base
            i = off;
        }
        const float4* p = reinterpret_cast<const float4*>(in) + (size_t)i * 2;
        const float4 a = p[0];
        const float4 b = p[1];
        short8 v;
        v[0] = (short)f2bf(a.x); v[1] = (short)f2bf(a.y);
        v[2] = (short)f2bf(a.z); v[3] = (short)f2bf(a.w);
        v[4] = (short)f2bf(b.x); v[5] = (short)f2bf(b.y);
        v[6] = (short)f2bf(b.z); v[7] = (short)f2bf(b.w);
        *(reinterpret_cast<short8*>(out) + i) = v;
    } else {                              // rope table: 4096*32 entries
        const int i = (blk - 6144) * 256 + threadIdx.x;
        const int t = i >> 5;
        const int j = i & 31;
        const float inv_freq = expf(-(float)j * 0.28782313662425575f); // ln(1e4)/32
        float s, c;
        sincosf((float)t * inv_freq, &s, &c);
        CS[i] = make_float2(c, s);
    }
}

// ---- shared K-loop machinery: 128x256 tile, 3-buffer counted-vmcnt ---------
// A tile 128x32 (2 cp16/thread), B tile 256x32 (4 cp16/thread) = 6 loads/step.
// per step: wait vmcnt(N) (6 main, 6/0 tail), pinned raw barrier, issue loads
// for k+2 into LB, ds_read BUF (a[4], b[8]), 32 MFMA. sched_barrier pins on
// both sides of s_barrier (s_barrier is not an IR memory fence; R15 race).
#define GEMM_STAGE(Ab, Wb, KK, BUF)                                           \
    do {                                                                      \
        _Pragma("unroll")                                                     \
        for (int j = 0; j < 2; ++j)                                           \
            cp16((Ab) + (size_t)(srow + j * 64) * C_ + (KK) + scol,           \
                 &Als[BUF][(j * 256 + tid) * 8]);                             \
        _Pragma("unroll")                                                     \
        for (int j = 0; j < 4; ++j)                                           \
            cp16((Wb) + (size_t)(srow + j * 64) * C_ + (KK) + scol,           \
                 &Bls[BUF][(j * 256 + tid) * 8]);                             \
    } while (0)

#define KSTEP(Ab, Wb, KK, BUF, LB, DOISSUE, VMN)                              \
    do {                                                                      \
        asm volatile("s_waitcnt vmcnt(" VMN ")" ::: "memory");                \
        __builtin_amdgcn_sched_barrier(0);                                    \
        __builtin_amdgcn_s_barrier();                                         \
        __builtin_amdgcn_sched_barrier(0);                                    \
        if (DOISSUE) GEMM_STAGE(Ab, Wb, (KK) + 64, LB);                       \
        short8 a[4], b[8];                                                    \
        _Pragma("unroll")                                                     \
        for (int i = 0; i < 4; ++i)                                           \
            a[i] = ld8(&Als[BUF][(wr + i * 16 + lr) * 32 + quad * 8]);        \
        _Pragma("unroll")                                                     \
        for (int j = 0; j < 8; ++j)                                           \
            b[j] = ld8(&Bls[BUF][(wc + j * 16 + lr) * 32 + quad * 8]);        \
        _Pragma("unroll")                                                     \
        for (int i = 0; i < 4; ++i)                                           \
            _Pragma("unroll")                                                 \
            for (int j = 0; j < 8; ++j)                                       \
                acc[i][j] = mfma16(a[i], b[j], acc[i][j]);                    \
    } while (0)

// 32 K-steps: 10x3 unrolled + 2 tail. Buffer = step%3; issue 2 ahead.
#define GEMM_MAINLOOP(Ab, Wb)                                                 \
    GEMM_STAGE(Ab, Wb, 0, 0);                                                 \
    GEMM_STAGE(Ab, Wb, 32, 1);                                                \
    for (int kk = 0; kk < 960; kk += 96) {                                    \
        KSTEP(Ab, Wb, kk,      0, 2, 1, "6");                                 \
        KSTEP(Ab, Wb, kk + 32, 1, 0, 1, "6");                                 \
        KSTEP(Ab, Wb, kk + 64, 2, 1, 1, "6");                                 \
    }                                                                         \
    KSTEP(Ab, Wb, 960, 0, 2, 0, "6");                                         \
    KSTEP(Ab, Wb, 992, 1, 0, 0, "0");

// ---------------------------------------------------------------------------
// GEMM: out[m][n] = sum_k A[m][k]*W[n][k]  (A @ W^T).
// 128x256 block tile, 4 waves (each 64x128), BK=32, 3-buffer counted-vmcnt
// pipeline. 1-D grid, XCD-swizzled, n-fastest decomp. ntile = N/256.
// ---------------------------------------------------------------------------
__global__ __launch_bounds__(256)
void gemm128_kernel(const bf16* __restrict__ A, const bf16* __restrict__ W,
                    void* __restrict__ out, int mode, int ntile, int cpx) {
    const int orig = blockIdx.x;
    const int swz  = (orig & 7) * cpx + (orig >> 3);
    const int m0   = (swz / ntile) * 128;
    const int n0   = (swz % ntile) * 256;
    const int tid  = threadIdx.x;
    const int lane = tid & 63;
    const int wave = tid >> 6;
    const int quad = lane >> 4;
    const int lr   = lane & 15;
    const int wr   = (wave >> 1) * 64;
    const int wc   = (wave & 1) * 128;

    __shared__ __align__(16) bf16 Als[3][128 * 32];
    __shared__ __align__(16) bf16 Bls[3][256 * 32];

    const int srow = tid >> 2;          // 0..63 (j adds 64)
    const int scol = (tid & 3) * 8;

    floatx4 acc[4][8];
#pragma unroll
    for (int i = 0; i < 4; ++i)
#pragma unroll
        for (int j = 0; j < 8; ++j) acc[i][j] = floatx4{0.f, 0.f, 0.f, 0.f};

    const bf16* Ab = A + (size_t)m0 * C_;
    const bf16* Wb = W + (size_t)n0 * C_;

    GEMM_MAINLOOP(Ab, Wb)

    if (mode == 0) {
        bf16* ob = (bf16*)out;
#pragma unroll
        for (int j = 0; j < 8; ++j) {
            const int col = n0 + wc + j * 16 + lr;
#pragma unroll
            for (int i = 0; i < 4; ++i)
#pragma unroll
                for (int r = 0; r < 4; ++r) {
                    const int m = m0 + wr + i * 16 + quad * 4 + r;
                    ob[(size_t)m * C_ + col] = __float2bfloat16(acc[i][j][r]);
                }
        }
    } else {
        float* of = (float*)out;
#pragma unroll
        for (int j = 0; j < 8; ++j) {
            const int col = n0 + wc + j * 16 + lr;
#pragma unroll
            for (int i = 0; i < 4; ++i)
#pragma unroll
                for (int r = 0; r < 4; ++r) {
                    const int m = m0 + wr + i * 16 + quad * 4 + r;
                    of[(size_t)m * C_ + col] = acc[i][j][r];
                }
        }
    }
}

// ---------------------------------------------------------------------------
// Fused QKV projection GEMM + inline RoPE. W = [wq;wk;wv] contiguous
// (3072 x 1024); out segments Q (flat, roped+scaled), K (flat, roped),
// Vt ([b][h][d][t]) contiguous from Qbase. grid 768, XCD-swizzled (cpx=96),
// n-fastest over 12 n-tiles of 256 (256 | 1024 so no segment straddle).
// RoPE pair (d, d+32) lane-local: pairs (j, j+2) for j in {0,1,4,5}.
// ---------------------------------------------------------------------------
__global__ __launch_bounds__(256)
void gemm_qkv_kernel(const bf16* __restrict__ A, const bf16* __restrict__ W,
                     bf16* __restrict__ Qbase, const float2* __restrict__ CS) {
    const int orig = blockIdx.x;
    const int swz  = (orig & 7) * 96 + (orig >> 3);
    const int m0   = (swz / 12) * 128;
    const int n0g  = (swz % 12) * 256;    // 0..2816
    const int tid  = threadIdx.x;
    const int lane = tid & 63;
    const int wave = tid >> 6;
    const int quad = lane >> 4;
    const int lr   = lane & 15;
    const int wr   = (wave >> 1) * 64;
    const int wc   = (wave & 1) * 128;

    __shared__ __align__(16) bf16 Als[3][128 * 32];
    __shared__ __align__(16) bf16 Bls[3][256 * 32];

    const int srow = tid >> 2;
    const int scol = (tid & 3) * 8;

    floatx4 acc[4][8];
#pragma unroll
    for (int i = 0; i < 4; ++i)
#pragma unroll
        for (int j = 0; j < 8; ++j) acc[i][j] = floatx4{0.f, 0.f, 0.f, 0.f};

    const bf16* Ab = A + (size_t)m0 * C_;
    const bf16* Wb = W + (size_t)n0g * C_;

    GEMM_MAINLOOP(Ab, Wb)

    const int seg = n0g >> 10;           // 0:Q 1:K 2:V
    const int n0  = n0g & 1023;
    if (seg < 2) {
        bf16* ob = Qbase + (size_t)seg * M_ * C_;
        const float scale = (seg == 0) ? QSCALE : 1.0f;
        const int tb = (m0 & 4095) + wr + quad * 4;
        const int jps[4] = {0, 1, 4, 5};
#pragma unroll
        for (int jj = 0; jj < 4; ++jj) {          // rotation pair (jp, jp+2)
            const int jp   = jps[jj];
            const int col  = n0 + wc + jp * 16 + lr;
            const int jcol = (jp & 1) * 16 + lr;   // d in 0..31
#pragma unroll
            for (int i = 0; i < 4; ++i) {
#pragma unroll
                for (int r = 0; r < 4; ++r) {
                    const int t = tb + i * 16 + r;
                    const float2 cs = CS[t * 32 + jcol];
                    const float q1 = acc[i][jp][r];
                    const float q2 = acc[i][jp + 2][r];
                    const int m = m0 + wr + i * 16 + quad * 4 + r;
                    ob[(size_t)m * C_ + col] =
                        __float2bfloat16((q1 * cs.x - q2 * cs.y) * scale);
                    ob[(size_t)m * C_ + col + 32] =
                        __float2bfloat16((q2 * cs.x + q1 * cs.y) * scale);
                }
            }
        }
    } else {
        unsigned short* ob = (unsigned short*)(Qbase + (size_t)2 * M_ * C_);
        const int b2 = m0 >> 12;
#pragma unroll
        for (int j = 0; j < 8; ++j) {
            const int n = n0 + wc + j * 16 + lr;
            const int h = n >> 6;
            const int d = n & 63;
#pragma unroll
            for (int i = 0; i < 4; ++i) {
                const int t0 = (m0 & 4095) + wr + i * 16 + quad * 4;
                ushort4 v;
                v.x = f2bf(acc[i][j][0]); v.y = f2bf(acc[i][j][1]);
                v.z = f2bf(acc[i][j][2]); v.w = f2bf(acc[i][j][3]);
                size_t idx = ((size_t)((b2 * 16 + h) * 64 + d)) * T_ + t0;
                *reinterpret_cast<ushort4*>(ob + idx) = v;
            }
        }
    }
}

// ---------------------------------------------------------------------------
// Flash attention: 4 waves x 32 q = 128 q rows per block, one (b,h).
// Stage = 64 kv; K and V 64x64 bf16 tiles in XOR-swizzled LDS (no pad):
// 16B chunk c of row r stored at physical chunk c^(r&7). Double-buffered,
// ONE raw barrier per stage (lgkm drain only; vmcnt rides through).
// ---------------------------------------------------------------------------
__global__ __launch_bounds__(256)
void attn_kernel(const bf16* __restrict__ Q, const bf16* __restrict__ K,
                 const bf16* __restrict__ Vt, bf16* __restrict__ AO) {
    const int tid  = threadIdx.x;
    const int lane = tid & 63;
    const int wave = tid >> 6;
    const int quad = lane >> 4;
    const int lr   = lane & 15;
    const int bh   = blockIdx.y;
    const int b    = bh >> 4;
    const int h    = bh & 15;
    const int q0   = blockIdx.x * 128 + wave * 32;   // 32 q rows per wave

    const bf16* Qb = Q + (size_t)b * T_ * C_ + h * 64;
    const bf16* Kb = K + (size_t)b * T_ * C_ + h * 64;
    const bf16* Vb = Vt + (size_t)bh * 64 * T_;

#if USE_K16
    __shared__ __align__(16) bf16 Kls[2][64 * 64];
    __shared__ __align__(16) bf16 Vls[2][64 * 64];

    // staging: thread -> rows {srow, srow+32}, logical chunk sc (16B)
    const int srow  = tid >> 3;              // 0..31
    const int sc    = tid & 7;
    const int sphys = (sc ^ (srow & 7)) * 8; // physical chunk offset (bf16)
    const int soff0 = srow * 64 + sphys;
    const int soff1 = (srow + 32) * 64 + sphys;  // (srow+32)&7 == srow&7

    // v_perm selector for pack2bf, kept in SGPR (hoisted out of the loop)
    const unsigned psel = 0x07060302u;
    // constants: zero C operand for QK, bf16 ones for row-sum MFMA
    const floatx4 FZ = {0.f, 0.f, 0.f, 0.f};
    const int one2 = 0x3F803F80;
    const short8 VONE = i2s8(one2, one2, one2, one2);

    short8 aq[2][2];
#pragma unroll
    for (int t = 0; t < 2; ++t) {
        aq[t][0] = ld8(Qb + (size_t)(q0 + t * 16 + lr) * C_ + quad * 8);
        aq[t][1] = ld8(Qb + (size_t)(q0 + t * 16 + lr) * C_ + 32 + quad * 8);
    }

    floatx4 O[2][4];
#pragma unroll
    for (int t = 0; t < 2; ++t)
#pragma unroll
        for (int dt = 0; dt < 4; ++dt) O[t][dt] = floatx4{0.f, 0.f, 0.f, 0.f};
    floatx4 Osum[2] = {{0.f, 0.f, 0.f, 0.f}, {0.f, 0.f, 0.f, 0.f}};

    // hoisted per-lane swizzled LDS element offsets (loop-invariant)
    const int lr7    = lr & 7;
    const int kchunk = (quad ^ lr7) * 8;     // K: logical chunk = quad
    const int vsub   = (quad & 1) * 4;
    const int vbq    = quad >> 1;
    const int kel0   = lr * 64 + kchunk;     // + kk*1024 imm
    const int kel1   = kel0 ^ 32;
    int velk[4];                             // constant-indexed only
#pragma unroll
    for (int kk = 0; kk < 4; ++kk)
        velk[kk] = lr * 64 + (((2 * kk + vbq) ^ lr7) * 8) + vsub;  // + dt*1024 imm

    short8 kr0, kr1, vr0, vr1;
#define LOAD_STAGE(kv0)                                              \
    do {                                                             \
        kr0 = ld8(Kb + (size_t)((kv0) + srow) * C_ + sc * 8);        \
        kr1 = ld8(Kb + (size_t)((kv0) + srow + 32) * C_ + sc * 8);   \
        vr0 = ld8(Vb + (size_t)srow * T_ + (kv0) + sc * 8);          \
        vr1 = ld8(Vb + (size_t)(srow + 32) * T_ + (kv0) + sc * 8);   \
    } while (0)
#define STORE_STAGE(p)                                               \
    do {                                                             \
        st8(&Kls[p][soff0], kr0);                                    \
        st8(&Kls[p][soff1], kr1);                                    \
        st8(&Vls[p][soff0], vr0);                                    \
        st8(&Vls[p][soff1], vr1);                                    \
    } while (0)

// raw barrier: drain LDS ops only; global prefetch stays in flight (vmcnt)
#define BAR()                                                        \
    do {                                                             \
        asm volatile("s_waitcnt lgkmcnt(0)" ::: "memory");           \
        __builtin_amdgcn_s_barrier();                                \
    } while (0)

// compute one 64-kv stage from compile-time buffer P
#define COMPUTE(P)                                                            \
    do {                                                                      \
        const bf16* Ks = Kls[P];                                              \
        const bf16* Vs = Vls[P];                                              \
        int prlo[2][4], prhi[2][4];                                           \
        _Pragma("unroll")                                                     \
        for (int kk = 0; kk < 4; ++kk) {                                      \
            const short8 kf0 = ld8(Ks + kk * 1024 + kel0);                    \
            const short8 kf1 = ld8(Ks + kk * 1024 + kel1);                    \
            floatx4 s0 = mfma16(kf0, aq[0][0], FZ);                           \
            s0 = mfma16(kf1, aq[0][1], s0);                                   \
            floatx4 s1 = mfma16(kf0, aq[1][0], FZ);                           \
            s1 = mfma16(kf1, aq[1][1], s1);                                   \
            const float e0 = EXP2(s0[0]), e1 = EXP2(s0[1]);                   \
            const float e2 = EXP2(s0[2]), e3 = EXP2(s0[3]);                   \
            prlo[0][kk] = pack2bf(e0, e1, psel);                              \
            prhi[0][kk] = pack2bf(e2, e3, psel);                              \
            const float f0 = EXP2(s1[0]), f1 = EXP2(s1[1]);                   \
            const float f2 = EXP2(s1[2]), f3 = EXP2(s1[3]);                   \
            prlo[1][kk] = pack2bf(f0, f1, psel);                              \
            prhi[1][kk] = pack2bf(f2, f3, psel);                              \
        }                                                                     \
        /* row sums: k-permutation-invariant -> feed packed P into 16x16x32 */\
        Osum[0] = mfma16(i2s8(prlo[0][0], prhi[0][0], prlo[0][1], prhi[0][1]),\
                         VONE, Osum[0]);                                      \
        Osum[0] = mfma16(i2s8(prlo[0][2], prhi[0][2], prlo[0][3], prhi[0][3]),\
                         VONE, Osum[0]);                                      \
        Osum[1] = mfma16(i2s8(prlo[1][0], prhi[1][0], prlo[1][1], prhi[1][1]),\
                         VONE, Osum[1]);                                      \
        Osum[1] = mfma16(i2s8(prlo[1][2], prhi[1][2], prlo[1][3], prhi[1][3]),\
                         VONE, Osum[1]);                                      \
        __builtin_amdgcn_s_setprio(1);                                        \
        _Pragma("unroll")                                                     \
        for (int dt = 0; dt < 4; ++dt) {                                      \
            _Pragma("unroll")                                                 \
            for (int kk = 0; kk < 4; ++kk) {                                  \
                const short4v vf = ld4(Vs + dt * 1024 + velk[kk]);            \
                O[0][dt] = mfma_k16(i2s4(prlo[0][kk], prhi[0][kk]), vf, O[0][dt]); \
                O[1][dt] = mfma_k16(i2s4(prlo[1][kk], prhi[1][kk]), vf, O[1][dt]); \
            }                                                                 \
        }                                                                     \
        __builtin_amdgcn_s_setprio(0);                                        \
    } while (0)

    LOAD_STAGE(0);
    STORE_STAGE(0);
    LOAD_STAGE(64);
    BAR();

    constexpr int NS = T_ / 64;
    for (int s = 0; s < NS; s += 2) {
        // even stage: compute buffer 0
        if (s + 1 < NS) STORE_STAGE(1);          // buffer last read at s-1
        if (s + 2 < NS) LOAD_STAGE((s + 2) * 64);
        COMPUTE(0);
        BAR();
        // odd stage: compute buffer 1
        if (s + 2 < NS) STORE_STAGE(0);
        if (s + 3 < NS) LOAD_STAGE((s + 3) * 64);
        COMPUTE(1);
        BAR();
    }

    // epilogue: lane (quad,lr) holds Osum[t][r] for q-row = quad*4+r directly
#pragma unroll
    for (int t = 0; t < 2; ++t) {
#pragma unroll
        for (int r = 0; r < 4; ++r) {
            const float inv = 1.0f / fmaxf(Osum[t][r], 1e-30f);
            const size_t row =
                (size_t)(b * T_ + q0 + t * 16 + quad * 4 + r) * C_ + h * 64;
            AO[row + 0  + lr] = __float2bfloat16(O[t][0][r] * inv);
            AO[row + 16 + lr] = __float2bfloat16(O[t][1][r] * inv);
            AO[row + 32 + lr] = __float2bfloat16(O[t][2][r] * inv);
            AO[row + 48 + lr] = __float2bfloat16(O[t][3][r] * inv);
        }
    }
#undef LOAD_STAGE
#undef STORE_STAGE
#undef COMPUTE
#undef BAR
#else
    // Fallback (no 16x16x16 builtin): LDS P round-trip path, exp2-based.
    __shared__ __align__(16) unsigned short Pbuf[4][512];
    unsigned short* Pw = Pbuf[wave];
    for (int half = 0; half < 2; ++half) {
        const int qh = q0 + half * 16;
        const short8 aq0 = ld8(Qb + (size_t)(qh + lr) * C_ + quad * 8);
        const short8 aq1 = ld8(Qb + (size_t)(qh + lr) * C_ + 32 + quad * 8);
        floatx4 O0 = {0,0,0,0}, O1 = {0,0,0,0}, O2 = {0,0,0,0}, O3 = {0,0,0,0};
        float lrun[4] = {0.f, 0.f, 0.f, 0.f};
        for (int kv = 0; kv < T_; kv += 32) {
            floatx4 S0 = {0,0,0,0}, S1 = {0,0,0,0};
            const bf16* k0 = Kb + (size_t)(kv + lr) * C_ + quad * 8;
            const bf16* k1 = Kb + (size_t)(kv + 16 + lr) * C_ + quad * 8;
            S0 = mfma16(aq0, ld8(k0), S0);
            S0 = mfma16(aq1, ld8(k0 + 32), S0);
            S1 = mfma16(aq0, ld8(k1), S1);
            S1 = mfma16(aq1, ld8(k1 + 32), S1);
#pragma unroll
            for (int r = 0; r < 4; ++r) {
                const float e0 = exp2f(S0[r]);
                const float e1 = exp2f(S1[r]);
                lrun[r] += e0 + e1;
                const int row = quad * 4 + r;
                Pw[row * 32 + lr]      = f2bf(e0);
                Pw[row * 32 + 16 + lr] = f2bf(e1);
            }
            __syncthreads();
            const short8 ap = *reinterpret_cast<const short8*>(Pw + lr * 32 + quad * 8);
            O0 = mfma16(ap, ld8(Vb + (size_t)(lr)      * T_ + kv + quad * 8), O0);
            O1 = mfma16(ap, ld8(Vb + (size_t)(16 + lr) * T_ + kv + quad * 8), O1);
            O2 = mfma16(ap, ld8(Vb + (size_t)(32 + lr) * T_ + kv + quad * 8), O2);
            O3 = mfma16(ap, ld8(Vb + (size_t)(48 + lr) * T_ + kv + quad * 8), O3);
            __syncthreads();
        }
#pragma unroll
        for (int r = 0; r < 4; ++r) {
            float l = lrun[r];
            l += __shfl_xor(l, 1); l += __shfl_xor(l, 2);
            l += __shfl_xor(l, 4); l += __shfl_xor(l, 8);
            const float inv = 1.0f / fmaxf(l, 1e-30f);
            const size_t row = (size_t)(b * T_ + qh + quad * 4 + r) * C_ + h * 64;
            AO[row + 0  + lr] = __float2bfloat16(O0[r] * inv);
            AO[row + 16 + lr] = __float2bfloat16(O1[r] * inv);
            AO[row + 32 + lr] = __float2bfloat16(O2[r] * inv);
            AO[row + 48 + lr] = __float2bfloat16(O3[r] * inv);
        }
    }
#endif
}

// ---------------------------------------------------------------------------
extern "C" void kernel_launch(void* const* d_in, const int* in_sizes, int n_in,
                              void* d_out, int out_size, void* d_ws, size_t ws_size,
                              hipStream_t stream) {
    const float* x  = (const float*)d_in[0];
    const float* wq = (const float*)d_in[1];
    const float* wk = (const float*)d_in[2];
    const float* wv = (const float*)d_in[3];
    const float* wo = (const float*)d_in[4];
    float* out = (float*)d_out;

    bf16* xb  = (bf16*)d_ws;
    bf16* wqb = xb  + (size_t)M_ * C_;
    bf16* wkb = wqb + (size_t)C_ * C_;
    bf16* wvb = wkb + (size_t)C_ * C_;
    bf16* wob = wvb + (size_t)C_ * C_;
    bf16* Q   = wob + (size_t)C_ * C_;
    bf16* K   = Q   + (size_t)M_ * C_;
    bf16* Vt  = K   + (size_t)M_ * C_;
    float2* CS = (float2*)(Vt + (size_t)M_ * C_);   // [4096][32] cos/sin, 1 MB
    bf16* AO  = xb;   // aliases xb; x dead after V GEMM

    // fused prep: x cvt (4096 blk) + weight cvt (2048 blk) + rope table (512)
    prep_kernel<<<6656, 256, 0, stream>>>(x, wq, wk, wv, wo, xb, wqb, CS);

    // fused QKV projection + RoPE: W = [wq;wk;wv] contiguous,
    // outs Q (roped+scaled), K (roped), Vt contiguous. XCD-swizzled.
    gemm_qkv_kernel<<<768, 256, 0, stream>>>(xb, wqb, Q, CS);

    attn_kernel<<<dim3(T_ / 128, 32), 256, 0, stream>>>(Q, K, Vt, AO);

    // final projection, fp32 out. XCD-swizzled: nwg=256, cpx=32, ntile=4.
    gemm128_kernel<<<256, 256, 0, stream>>>(AO, wob, out, 2, 4, 32);
}

// Round 10
// 371.171 us; speedup vs baseline: 1.1067x; 1.1067x over previous
//
#include <hip/hip_runtime.h>
#include <hip/hip_bf16.h>
#include <math.h>

// B=2, T=4096, DIM=1024, H=16, D=64. fp32 in/out; bf16 MFMA internally.
// out = softmax((RoPE(xWq^T) RoPE(xWk^T)^T)/8) (xWv^T) Wo^T
// Round 19 (revert R18 truncation; keep R16 structure):
//  - P pack MUST be round-half-up (+0x8000 then v_perm). Truncation (R18,
//    4.7e-2) and cvt_pk RNE-as-written (R10, 2.7e-2) both blow the 3.5e-3
//    threshold; half-up measures 9.8e-4. Do not touch P rounding again.
//  - GEMM KSTEP: ds_reads of current buffer issued BEFORE cp16 prefetch
//    issue (critical path = ds_read->MFMA; cp16 issue overlaps MFMA).
//    Ring safety is order-independent within a step (re-derived).
//  - otherwise identical to R16 (best passing, 376.1us).

typedef __attribute__((ext_vector_type(8))) short short8;   // 8 x bf16
typedef __attribute__((ext_vector_type(4))) short short4v;  // 4 x bf16
typedef __attribute__((ext_vector_type(4))) float floatx4;  // MFMA acc

using bf16 = __hip_bfloat16;

static constexpr int T_ = 4096;
static constexpr int C_ = 1024;   // DIM
static constexpr int M_ = 8192;   // B*T
static constexpr float QSCALE = 0.125f * 1.44269504088896340736f; // 1/8*log2(e)

#if __has_builtin(__builtin_amdgcn_mfma_f32_16x16x16bf16_1k)
#define USE_K16 1
#else
#define USE_K16 0
#endif

#if __has_builtin(__builtin_amdgcn_exp2f)
#define EXP2 __builtin_amdgcn_exp2f
#else
#define EXP2 exp2f
#endif

__device__ __forceinline__ floatx4 mfma16(short8 a, short8 b, floatx4 c) {
    return __builtin_amdgcn_mfma_f32_16x16x32_bf16(a, b, c, 0, 0, 0);
}
#if USE_K16
__device__ __forceinline__ floatx4 mfma_k16(short4v a, short4v b, floatx4 c) {
    return __builtin_amdgcn_mfma_f32_16x16x16bf16_1k(a, b, c, 0, 0, 0);
}
#endif

__device__ __forceinline__ short8 ld8(const bf16* p) {
    return *reinterpret_cast<const short8*>(p);
}
__device__ __forceinline__ short4v ld4(const bf16* p) {
    return *reinterpret_cast<const short4v*>(p);
}
__device__ __forceinline__ void st8(bf16* p, short8 v) {
    *reinterpret_cast<short8*>(p) = v;
}
__device__ __forceinline__ unsigned short f2bf(float x) {
    bf16 h = __float2bfloat16(x);
    return reinterpret_cast<unsigned short&>(h);
}

// two fp32 -> packed bf16 pair (round-half-up; inputs positive finite).
// D[15:0]=bf16(a), D[31:16]=bf16(b). 2x v_add + v_perm_b32 (sel in SGPR):
// v_perm combined bytes: 0-3 = S1(=ua), 4-7 = S0(=ub); take {2,3,6,7}.
// PROVEN numerics (9.8e-4); truncation/cvt_pk variants fail threshold.
__device__ __forceinline__ int pack2bf(float a, float b, unsigned sel) {
    const unsigned ua = __float_as_uint(a) + 0x8000u;
    const unsigned ub = __float_as_uint(b) + 0x8000u;
    int r;
    asm("v_perm_b32 %0, %1, %2, %3" : "=v"(r) : "v"(ub), "v"(ua), "s"(sel));
    return r;
}
__device__ __forceinline__ short4v i2s4(int lo, int hi) {
    union { int2 i; short4v s; } u;
    u.i.x = lo; u.i.y = hi;
    return u.s;
}
__device__ __forceinline__ short8 i2s8(int a, int b, int c, int d) {
    union { int4 i; short8 s; } u;
    u.i.x = a; u.i.y = b; u.i.z = c; u.i.w = d;
    return u.s;
}

// async global->LDS, 16 B per lane (global_load_lds_dwordx4).
__device__ __forceinline__ void cp16(const bf16* g, bf16* l) {
    __builtin_amdgcn_global_load_lds(
        (const __attribute__((address_space(1))) void*)g,
        (__attribute__((address_space(3))) void*)l, 16, 0, 0);
}

// ---------------------------------------------------------------------------
// Fused prep: blocks [0,4096) cvt x; [4096,6144) cvt 4 weights;
// [6144,6656) rope cos/sin table. 256 thr, 8 fp32->bf16 per thread.
// ---------------------------------------------------------------------------
__global__ __launch_bounds__(256)
void prep_kernel(const float* __restrict__ x,
                 const float* __restrict__ wq, const float* __restrict__ wk,
                 const float* __restrict__ wv, const float* __restrict__ wo,
                 bf16* __restrict__ xb, bf16* __restrict__ wqb,
                 float2* __restrict__ CS) {
    const int blk = blockIdx.x;
    if (blk < 6144) {
        const float* in;
        bf16* out;
        int i;
        if (blk < 4096) {                 // x: 2^20 groups of 8
            i = blk * 256 + threadIdx.x;
            in = x; out = xb;
        } else {                          // weights: 4 segs of 2^17 groups
            i = (blk - 4096) * 256 + threadIdx.x;
            const int seg = i >> 17;
            const int off = i & 131071;
            in = (seg == 0) ? wq : (seg == 1) ? wk : (seg == 2) ? wv : wo;
            out = wqb + (size_t)i * 8 - (size_t)off * 8;  // seg base
            i = off;
        }
        const float4* p = reinterpret_cast<const float4*>(in) + (size_t)i * 2;
        const float4 a = p[0];
        const float4 b = p[1];
        short8 v;
        v[0] = (short)f2bf(a.x); v[1] = (short)f2bf(a.y);
        v[2] = (short)f2bf(a.z); v[3] = (short)f2bf(a.w);
        v[4] = (short)f2bf(b.x); v[5] = (short)f2bf(b.y);
        v[6] = (short)f2bf(b.z); v[7] = (short)f2bf(b.w);
        *(reinterpret_cast<short8*>(out) + i) = v;
    } else {                              // rope table: 4096*32 entries
        const int i = (blk - 6144) * 256 + threadIdx.x;
        const int t = i >> 5;
        const int j = i & 31;
        const float inv_freq = expf(-(float)j * 0.28782313662425575f); // ln(1e4)/32
        float s, c;
        sincosf((float)t * inv_freq, &s, &c);
        CS[i] = make_float2(c, s);
    }
}

// ---- shared K-loop machinery for the 3-buffer counted-vmcnt GEMMs ----------
// per step: wait vmcnt(N) (N=4 main loop, 0 last), pinned raw barrier,
// ds_read BUF (critical path first), issue loads for k+2 into LB, 16 MFMA.
// Buffer indices compile-time. sched_barrier(0) on both sides of s_barrier:
// s_barrier is NOT an IR-level memory fence; without pins the compiler may
// hoist cp16/ds_read into the waitcnt->barrier window (R15 race).
#define GEMM_PROLOGUE(Ab, Wb)                                                 \
    _Pragma("unroll")                                                         \
    for (int j = 0; j < 2; ++j) {                                             \
        const int row = srow + j * 64;                                        \
        cp16((Ab) + (size_t)row * C_ + scol, &Als[0][(j * 256 + tid) * 8]);   \
        cp16((Wb) + (size_t)row * C_ + scol, &Bls[0][(j * 256 + tid) * 8]);   \
    }                                                                         \
    _Pragma("unroll")                                                         \
    for (int j = 0; j < 2; ++j) {                                             \
        const int row = srow + j * 64;                                        \
        cp16((Ab) + (size_t)row * C_ + 32 + scol, &Als[1][(j * 256 + tid) * 8]); \
        cp16((Wb) + (size_t)row * C_ + 32 + scol, &Bls[1][(j * 256 + tid) * 8]); \
    }

#define KSTEP(Ab, Wb, KK, BUF, LB, DOISSUE, VMN)                              \
    do {                                                                      \
        asm volatile("s_waitcnt vmcnt(" VMN ")" ::: "memory");                \
        __builtin_amdgcn_sched_barrier(0);                                    \
        __builtin_amdgcn_s_barrier();                                         \
        __builtin_amdgcn_sched_barrier(0);                                    \
        short8 a[4], b[4];                                                    \
        _Pragma("unroll")                                                     \
        for (int i = 0; i < 4; ++i)                                           \
            a[i] = ld8(&Als[BUF][(wr + i * 16 + lr) * 32 + quad * 8]);        \
        _Pragma("unroll")                                                     \
        for (int j = 0; j < 4; ++j)                                           \
            b[j] = ld8(&Bls[BUF][(wc + j * 16 + lr) * 32 + quad * 8]);        \
        if (DOISSUE) {                                                        \
            _Pragma("unroll")                                                 \
            for (int j = 0; j < 2; ++j) {                                     \
                const int row = srow + j * 64;                                \
                cp16((Ab) + (size_t)row * C_ + (KK) + 64 + scol,              \
                     &Als[LB][(j * 256 + tid) * 8]);                          \
                cp16((Wb) + (size_t)row * C_ + (KK) + 64 + scol,              \
                     &Bls[LB][(j * 256 + tid) * 8]);                          \
            }                                                                 \
        }                                                                     \
        _Pragma("unroll")                                                     \
        for (int i = 0; i < 4; ++i)                                           \
            _Pragma("unroll")                                                 \
            for (int j = 0; j < 4; ++j)                                       \
                acc[i][j] = mfma16(a[i], b[j], acc[i][j]);                    \
    } while (0)

#define GEMM_MAINLOOP(Ab, Wb)                                                 \
    GEMM_PROLOGUE(Ab, Wb)                                                     \
    for (int kk = 0; kk < 960; kk += 96) {                                    \
        KSTEP(Ab, Wb, kk,      0, 2, 1, "4");                                 \
        KSTEP(Ab, Wb, kk + 32, 1, 0, 1, "4");                                 \
        KSTEP(Ab, Wb, kk + 64, 2, 1, 1, "4");                                 \
    }                                                                         \
    KSTEP(Ab, Wb, 960, 0, 2, 0, "4");                                         \
    KSTEP(Ab, Wb, 992, 1, 0, 0, "0");

// ---------------------------------------------------------------------------
// GEMM: out[m][n] = sum_k A[m][k]*W[n][k]  (A @ W^T).
// 128x128 block tile, 4 waves (each 64x64), BK=32, 3-buffer counted-vmcnt
// pipeline. 1-D grid, XCD-swizzled, n-fastest decomp.
// ---------------------------------------------------------------------------
__global__ __launch_bounds__(256)
void gemm128_kernel(const bf16* __restrict__ A, const bf16* __restrict__ W,
                    void* __restrict__ out, int mode, int ntile, int cpx) {
    const int orig = blockIdx.x;
    const int swz  = (orig & 7) * cpx + (orig >> 3);
    const int m0   = (swz / ntile) * 128;
    const int n0   = (swz % ntile) * 128;
    const int tid  = threadIdx.x;
    const int lane = tid & 63;
    const int wave = tid >> 6;
    const int quad = lane >> 4;
    const int lr   = lane & 15;
    const int wr   = (wave >> 1) * 64;
    const int wc   = (wave & 1) * 64;

    __shared__ __align__(16) bf16 Als[3][128 * 32];
    __shared__ __align__(16) bf16 Bls[3][128 * 32];

    const int srow = tid >> 2;          // 0..63 (j adds 64)
    const int scol = (tid & 3) * 8;

    floatx4 acc[4][4];
#pragma unroll
    for (int i = 0; i < 4; ++i)
#pragma unroll
        for (int j = 0; j < 4; ++j) acc[i][j] = floatx4{0.f, 0.f, 0.f, 0.f};

    const bf16* Ab = A + (size_t)m0 * C_;
    const bf16* Wb = W + (size_t)n0 * C_;

    GEMM_MAINLOOP(Ab, Wb)

    if (mode == 0) {
        bf16* ob = (bf16*)out;
#pragma unroll
        for (int j = 0; j < 4; ++j) {
            const int col = n0 + wc + j * 16 + lr;
#pragma unroll
            for (int i = 0; i < 4; ++i)
#pragma unroll
                for (int r = 0; r < 4; ++r) {
                    const int m = m0 + wr + i * 16 + quad * 4 + r;
                    ob[(size_t)m * C_ + col] = __float2bfloat16(acc[i][j][r]);
                }
        }
    } else {
        float* of = (float*)out;
#pragma unroll
        for (int j = 0; j < 4; ++j) {
            const int col = n0 + wc + j * 16 + lr;
#pragma unroll
            for (int i = 0; i < 4; ++i)
#pragma unroll
                for (int r = 0; r < 4; ++r) {
                    const int m = m0 + wr + i * 16 + quad * 4 + r;
                    of[(size_t)m * C_ + col] = acc[i][j][r];
                }
        }
    }
}

// ---------------------------------------------------------------------------
// Fused QKV projection GEMM + inline RoPE. W = [wq;wk;wv] contiguous
// (3072 x 1024); out segments Q (flat, roped+scaled), K (flat, roped),
// Vt ([b][h][d][t]) contiguous from Qbase. 1-D grid 1536, XCD-swizzled
// (cpx=192), n-fastest decomposition over 24 n-tiles.
// RoPE pair (d, d+32) is lane-local: acc[i][j][r] vs acc[i][j+2][r].
// ---------------------------------------------------------------------------
__global__ __launch_bounds__(256)
void gemm_qkv_kernel(const bf16* __restrict__ A, const bf16* __restrict__ W,
                     bf16* __restrict__ Qbase, const float2* __restrict__ CS) {
    const int orig = blockIdx.x;
    const int swz  = (orig & 7) * 192 + (orig >> 3);
    const int m0   = (swz / 24) * 128;
    const int n0g  = (swz % 24) * 128;    // 0..3071
    const int tid  = threadIdx.x;
    const int lane = tid & 63;
    const int wave = tid >> 6;
    const int quad = lane >> 4;
    const int lr   = lane & 15;
    const int wr   = (wave >> 1) * 64;
    const int wc   = (wave & 1) * 64;

    __shared__ __align__(16) bf16 Als[3][128 * 32];
    __shared__ __align__(16) bf16 Bls[3][128 * 32];

    const int srow = tid >> 2;
    const int scol = (tid & 3) * 8;

    floatx4 acc[4][4];
#pragma unroll
    for (int i = 0; i < 4; ++i)
#pragma unroll
        for (int j = 0; j < 4; ++j) acc[i][j] = floatx4{0.f, 0.f, 0.f, 0.f};

    const bf16* Ab = A + (size_t)m0 * C_;
    const bf16* Wb = W + (size_t)n0g * C_;

    GEMM_MAINLOOP(Ab, Wb)

    const int seg = n0g >> 10;           // 0:Q 1:K 2:V
    const int n0  = n0g & 1023;
    if (seg < 2) {
        bf16* ob = Qbase + (size_t)seg * M_ * C_;
        const float scale = (seg == 0) ? QSCALE : 1.0f;
        const int tb = (m0 & 4095) + wr + quad * 4;
#pragma unroll
        for (int j = 0; j < 2; ++j) {             // rotation pair (j, j+2)
            const int col  = n0 + wc + j * 16 + lr;
            const int jcol = j * 16 + lr;          // d in 0..31
#pragma unroll
            for (int i = 0; i < 4; ++i) {
#pragma unroll
                for (int r = 0; r < 4; ++r) {
                    const int t = tb + i * 16 + r;
                    const float2 cs = CS[t * 32 + jcol];
                    const float q1 = acc[i][j][r];
                    const float q2 = acc[i][j + 2][r];
                    const int m = m0 + wr + i * 16 + quad * 4 + r;
                    ob[(size_t)m * C_ + col] =
                        __float2bfloat16((q1 * cs.x - q2 * cs.y) * scale);
                    ob[(size_t)m * C_ + col + 32] =
                        __float2bfloat16((q2 * cs.x + q1 * cs.y) * scale);
                }
            }
        }
    } else {
        unsigned short* ob = (unsigned short*)(Qbase + (size_t)2 * M_ * C_);
        const int b2 = m0 >> 12;
#pragma unroll
        for (int j = 0; j < 4; ++j) {
            const int n = n0 + wc + j * 16 + lr;
            const int h = n >> 6;
            const int d = n & 63;
#pragma unroll
            for (int i = 0; i < 4; ++i) {
                const int t0 = (m0 & 4095) + wr + i * 16 + quad * 4;
                ushort4 v;
                v.x = f2bf(acc[i][j][0]); v.y = f2bf(acc[i][j][1]);
                v.z = f2bf(acc[i][j][2]); v.w = f2bf(acc[i][j][3]);
                size_t idx = ((size_t)((b2 * 16 + h) * 64 + d)) * T_ + t0;
                *reinterpret_cast<ushort4*>(ob + idx) = v;
            }
        }
    }
}

// ---------------------------------------------------------------------------
// Flash attention: 4 waves x 32 q = 128 q rows per block, one (b,h).
// Stage = 64 kv; K and V 64x64 bf16 tiles in XOR-swizzled LDS (no pad):
// 16B chunk c of row r stored at physical chunk c^(r&7). Double-buffered,
// ONE raw barrier per stage (lgkm drain only; vmcnt rides through).
// ---------------------------------------------------------------------------
__global__ __launch_bounds__(256)
void attn_kernel(const bf16* __restrict__ Q, const bf16* __restrict__ K,
                 const bf16* __restrict__ Vt, bf16* __restrict__ AO) {
    const int tid  = threadIdx.x;
    const int lane = tid & 63;
    const int wave = tid >> 6;
    const int quad = lane >> 4;
    const int lr   = lane & 15;
    const int bh   = blockIdx.y;
    const int b    = bh >> 4;
    const int h    = bh & 15;
    const int q0   = blockIdx.x * 128 + wave * 32;   // 32 q rows per wave

    const bf16* Qb = Q + (size_t)b * T_ * C_ + h * 64;
    const bf16* Kb = K + (size_t)b * T_ * C_ + h * 64;
    const bf16* Vb = Vt + (size_t)bh * 64 * T_;

#if USE_K16
    __shared__ __align__(16) bf16 Kls[2][64 * 64];
    __shared__ __align__(16) bf16 Vls[2][64 * 64];

    // staging: thread -> rows {srow, srow+32}, logical chunk sc (16B)
    const int srow  = tid >> 3;              // 0..31
    const int sc    = tid & 7;
    const int sphys = (sc ^ (srow & 7)) * 8; // physical chunk offset (bf16)
    const int soff0 = srow * 64 + sphys;
    const int soff1 = (srow + 32) * 64 + sphys;  // (srow+32)&7 == srow&7

    // v_perm selector for pack2bf, kept in SGPR (hoisted out of the loop)
    const unsigned psel = 0x07060302u;
    // constants: zero C operand for QK, bf16 ones for row-sum MFMA
    const floatx4 FZ = {0.f, 0.f, 0.f, 0.f};
    const int one2 = 0x3F803F80;
    const short8 VONE = i2s8(one2, one2, one2, one2);

    short8 aq[2][2];
#pragma unroll
    for (int t = 0; t < 2; ++t) {
        aq[t][0] = ld8(Qb + (size_t)(q0 + t * 16 + lr) * C_ + quad * 8);
        aq[t][1] = ld8(Qb + (size_t)(q0 + t * 16 + lr) * C_ + 32 + quad * 8);
    }

    floatx4 O[2][4];
#pragma unroll
    for (int t = 0; t < 2; ++t)
#pragma unroll
        for (int dt = 0; dt < 4; ++dt) O[t][dt] = floatx4{0.f, 0.f, 0.f, 0.f};
    floatx4 Osum[2] = {{0.f, 0.f, 0.f, 0.f}, {0.f, 0.f, 0.f, 0.f}};

    // hoisted per-lane swizzled LDS element offsets (loop-invariant)
    const int lr7    = lr & 7;
    const int kchunk = (quad ^ lr7) * 8;     // K: logical chunk = quad
    const int vsub   = (quad & 1) * 4;
    const int vbq    = quad >> 1;
    const int kel0   = lr * 64 + kchunk;     // + kk*1024 imm
    const int kel1   = kel0 ^ 32;
    int velk[4];                             // constant-indexed only
#pragma unroll
    for (int kk = 0; kk < 4; ++kk)
        velk[kk] = lr * 64 + (((2 * kk + vbq) ^ lr7) * 8) + vsub;  // + dt*1024 imm

    short8 kr0, kr1, vr0, vr1;
#define LOAD_STAGE(kv0)                                              \
    do {                                                             \
        kr0 = ld8(Kb + (size_t)((kv0) + srow) * C_ + sc * 8);        \
        kr1 = ld8(Kb + (size_t)((kv0) + srow + 32) * C_ + sc * 8);   \
        vr0 = ld8(Vb + (size_t)srow * T_ + (kv0) + sc * 8);          \
        vr1 = ld8(Vb + (size_t)(srow + 32) * T_ + (kv0) + sc * 8);   \
    } while (0)
#define STORE_STAGE(p)                                               \
    do {                                                             \
        st8(&Kls[p][soff0], kr0);                                    \
        st8(&Kls[p][soff1], kr1);                                    \
        st8(&Vls[p][soff0], vr0);                                    \
        st8(&Vls[p][soff1], vr1);                                    \
    } while (0)

// raw barrier: drain LDS ops only; global prefetch stays in flight (vmcnt)
#define BAR()                                                        \
    do {                                                             \
        asm volatile("s_waitcnt lgkmcnt(0)" ::: "memory");           \
        __builtin_amdgcn_s_barrier();                                \
    } while (0)

// compute one 64-kv stage from compile-time buffer P
#define COMPUTE(P)                                                            \
    do {                                                                      \
        const bf16* Ks = Kls[P];                                              \
        const bf16* Vs = Vls[P];                                              \
        int prlo[2][4], prhi[2][4];                                           \
        _Pragma("unroll")                                                     \
        for (int kk = 0; kk < 4; ++kk) {                                      \
            const short8 kf0 = ld8(Ks + kk * 1024 + kel0);                    \
            const short8 kf1 = ld8(Ks + kk * 1024 + kel1);                    \
            floatx4 s0 = mfma16(kf0, aq[0][0], FZ);                           \
            s0 = mfma16(kf1, aq[0][1], s0);                                   \
            floatx4 s1 = mfma16(kf0, aq[1][0], FZ);                           \
            s1 = mfma16(kf1, aq[1][1], s1);                                   \
            const float e0 = EXP2(s0[0]), e1 = EXP2(s0[1]);                   \
            const float e2 = EXP2(s0[2]), e3 = EXP2(s0[3]);                   \
            prlo[0][kk] = pack2bf(e0, e1, psel);                              \
            prhi[0][kk] = pack2bf(e2, e3, psel);                              \
            const float f0 = EXP2(s1[0]), f1 = EXP2(s1[1]);                   \
            const float f2 = EXP2(s1[2]), f3 = EXP2(s1[3]);                   \
            prlo[1][kk] = pack2bf(f0, f1, psel);                              \
            prhi[1][kk] = pack2bf(f2, f3, psel);                              \
        }                                                                     \
        /* row sums: k-permutation-invariant -> feed packed P into 16x16x32 */\
        Osum[0] = mfma16(i2s8(prlo[0][0], prhi[0][0], prlo[0][1], prhi[0][1]),\
                         VONE, Osum[0]);                                      \
        Osum[0] = mfma16(i2s8(prlo[0][2], prhi[0][2], prlo[0][3], prhi[0][3]),\
                         VONE, Osum[0]);                                      \
        Osum[1] = mfma16(i2s8(prlo[1][0], prhi[1][0], prlo[1][1], prhi[1][1]),\
                         VONE, Osum[1]);                                      \
        Osum[1] = mfma16(i2s8(prlo[1][2], prhi[1][2], prlo[1][3], prhi[1][3]),\
                         VONE, Osum[1]);                                      \
        __builtin_amdgcn_s_setprio(1);                                        \
        _Pragma("unroll")                                                     \
        for (int dt = 0; dt < 4; ++dt) {                                      \
            _Pragma("unroll")                                                 \
            for (int kk = 0; kk < 4; ++kk) {                                  \
                const short4v vf = ld4(Vs + dt * 1024 + velk[kk]);            \
                O[0][dt] = mfma_k16(i2s4(prlo[0][kk], prhi[0][kk]), vf, O[0][dt]); \
                O[1][dt] = mfma_k16(i2s4(prlo[1][kk], prhi[1][kk]), vf, O[1][dt]); \
            }                                                                 \
        }                                                                     \
        __builtin_amdgcn_s_setprio(0);                                        \
    } while (0)

    LOAD_STAGE(0);
    STORE_STAGE(0);
    LOAD_STAGE(64);
    BAR();

    constexpr int NS = T_ / 64;
    for (int s = 0; s < NS; s += 2) {
        // even stage: compute buffer 0
        if (s + 1 < NS) STORE_STAGE(1);          // buffer last read at s-1
        if (s + 2 < NS) LOAD_STAGE((s + 2) * 64);
        COMPUTE(0);
        BAR();
        // odd stage: compute buffer 1
        if (s + 2 < NS) STORE_STAGE(0);
        if (s + 3 < NS) LOAD_STAGE((s + 3) * 64);
        COMPUTE(1);
        BAR();
    }

    // epilogue: lane (quad,lr) holds Osum[t][r] for q-row = quad*4+r directly
#pragma unroll
    for (int t = 0; t < 2; ++t) {
#pragma unroll
        for (int r = 0; r < 4; ++r) {
            const float inv = 1.0f / fmaxf(Osum[t][r], 1e-30f);
            const size_t row =
                (size_t)(b * T_ + q0 + t * 16 + quad * 4 + r) * C_ + h * 64;
            AO[row + 0  + lr] = __float2bfloat16(O[t][0][r] * inv);
            AO[row + 16 + lr] = __float2bfloat16(O[t][1][r] * inv);
            AO[row + 32 + lr] = __float2bfloat16(O[t][2][r] * inv);
            AO[row + 48 + lr] = __float2bfloat16(O[t][3][r] * inv);
        }
    }
#undef LOAD_STAGE
#undef STORE_STAGE
#undef COMPUTE
#undef BAR
#else
    // Fallback (no 16x16x16 builtin): LDS P round-trip path, exp2-based.
    __shared__ __align__(16) unsigned short Pbuf[4][512];
    unsigned short* Pw = Pbuf[wave];
    for (int half = 0; half < 2; ++half) {
        const int qh = q0 + half * 16;
        const short8 aq0 = ld8(Qb + (size_t)(qh + lr) * C_ + quad * 8);
        const short8 aq1 = ld8(Qb + (size_t)(qh + lr) * C_ + 32 + quad * 8);
        floatx4 O0 = {0,0,0,0}, O1 = {0,0,0,0}, O2 = {0,0,0,0}, O3 = {0,0,0,0};
        float lrun[4] = {0.f, 0.f, 0.f, 0.f};
        for (int kv = 0; kv < T_; kv += 32) {
            floatx4 S0 = {0,0,0,0}, S1 = {0,0,0,0};
            const bf16* k0 = Kb + (size_t)(kv + lr) * C_ + quad * 8;
            const bf16* k1 = Kb + (size_t)(kv + 16 + lr) * C_ + quad * 8;
            S0 = mfma16(aq0, ld8(k0), S0);
            S0 = mfma16(aq1, ld8(k0 + 32), S0);
            S1 = mfma16(aq0, ld8(k1), S1);
            S1 = mfma16(aq1, ld8(k1 + 32), S1);
#pragma unroll
            for (int r = 0; r < 4; ++r) {
                const float e0 = exp2f(S0[r]);
                const float e1 = exp2f(S1[r]);
                lrun[r] += e0 + e1;
                const int row = quad * 4 + r;
                Pw[row * 32 + lr]      = f2bf(e0);
                Pw[row * 32 + 16 + lr] = f2bf(e1);
            }
            __syncthreads();
            const short8 ap = *reinterpret_cast<const short8*>(Pw + lr * 32 + quad * 8);
            O0 = mfma16(ap, ld8(Vb + (size_t)(lr)      * T_ + kv + quad * 8), O0);
            O1 = mfma16(ap, ld8(Vb + (size_t)(16 + lr) * T_ + kv + quad * 8), O1);
            O2 = mfma16(ap, ld8(Vb + (size_t)(32 + lr) * T_ + kv + quad * 8), O2);
            O3 = mfma16(ap, ld8(Vb + (size_t)(48 + lr) * T_ + kv + quad * 8), O3);
            __syncthreads();
        }
#pragma unroll
        for (int r = 0; r < 4; ++r) {
            float l = lrun[r];
            l += __shfl_xor(l, 1); l += __shfl_xor(l, 2);
            l += __shfl_xor(l, 4); l += __shfl_xor(l, 8);
            const float inv = 1.0f / fmaxf(l, 1e-30f);
            const size_t row = (size_t)(b * T_ + qh + quad * 4 + r) * C_ + h * 64;
            AO[row + 0  + lr] = __float2bfloat16(O0[r] * inv);
            AO[row + 16 + lr] = __float2bfloat16(O1[r] * inv);
            AO[row + 32 + lr] = __float2bfloat16(O2[r] * inv);
            AO[row + 48 + lr] = __float2bfloat16(O3[r] * inv);
        }
    }
#endif
}

// ---------------------------------------------------------------------------
extern "C" void kernel_launch(void* const* d_in, const int* in_sizes, int n_in,
                              void* d_out, int out_size, void* d_ws, size_t ws_size,
                              hipStream_t stream) {
    const float* x  = (const float*)d_in[0];
    const float* wq = (const float*)d_in[1];
    const float* wk = (const float*)d_in[2];
    const float* wv = (const float*)d_in[3];
    const float* wo = (const float*)d_in[4];
    float* out = (float*)d_out;

    bf16* xb  = (bf16*)d_ws;
    bf16* wqb = xb  + (size_t)M_ * C_;
    bf16* wkb = wqb + (size_t)C_ * C_;
    bf16* wvb = wkb + (size_t)C_ * C_;
    bf16* wob = wvb + (size_t)C_ * C_;
    bf16* Q   = wob + (size_t)C_ * C_;
    bf16* K   = Q   + (size_t)M_ * C_;
    bf16* Vt  = K   + (size_t)M_ * C_;
    float2* CS = (float2*)(Vt + (size_t)M_ * C_);   // [4096][32] cos/sin, 1 MB
    bf16* AO  = xb;   // aliases xb; x dead after V GEMM

    // fused prep: x cvt (4096 blk) + weight cvt (2048 blk) + rope table (512)
    prep_kernel<<<6656, 256, 0, stream>>>(x, wq, wk, wv, wo, xb, wqb, CS);

    // fused QKV projection + RoPE: W = [wq;wk;wv] contiguous,
    // outs Q (roped+scaled), K (roped), Vt contiguous. XCD-swizzled.
    gemm_qkv_kernel<<<1536, 256, 0, stream>>>(xb, wqb, Q, CS);

    attn_kernel<<<dim3(T_ / 128, 32), 256, 0, stream>>>(Q, K, Vt, AO);

    // final projection, fp32 out. XCD-swizzled: nwg=512, cpx=64, ntile=8.
    gemm128_kernel<<<512, 256, 0, stream>>>(AO, wob, out, 2, 8, 64);
}

// Round 11
// 354.524 us; speedup vs baseline: 1.1587x; 1.0470x over previous
//
#include <hip/hip_runtime.h>
#include <hip/hip_bf16.h>
#include <math.h>

// B=2, T=4096, DIM=1024, H=16, D=64. fp32 in/out; bf16 MFMA internally.
// out = softmax((RoPE(xWq^T) RoPE(xWk^T)^T)/8) (xWv^T) Wo^T
// Round 20 (GEMM occupancy: 256x128 tile, 8 waves, 4 waves/SIMD):
//  - 128^2/4-wave GEMM = 48KB LDS -> 3 blocks/CU = 3 waves/SIMD. New: 256x128
//    tile, 512 thr, per-wave output still 64x64 (same inner loop, ~120 VGPR),
//    LDS 72KB -> 2 blocks/CU x 8 waves = 4 waves/SIMD (+33% latency hiding);
//    __launch_bounds__(512,4) pins VGPR <= 128. Half the blocks -> W-panel
//    refetch halves. vmcnt ring: 3 loads/thread/step -> 3/3/0.
//  - P pack stays round-half-up (+0x8000/v_perm): trunc (R18) and cvt_pk
//    (R10) both blow threshold. Do not touch.
//  - attn / prep unchanged (attn issue-saturated, 207.7us).

typedef __attribute__((ext_vector_type(8))) short short8;   // 8 x bf16
typedef __attribute__((ext_vector_type(4))) short short4v;  // 4 x bf16
typedef __attribute__((ext_vector_type(4))) float floatx4;  // MFMA acc

using bf16 = __hip_bfloat16;

static constexpr int T_ = 4096;
static constexpr int C_ = 1024;   // DIM
static constexpr int M_ = 8192;   // B*T
static constexpr float QSCALE = 0.125f * 1.44269504088896340736f; // 1/8*log2(e)

#if __has_builtin(__builtin_amdgcn_mfma_f32_16x16x16bf16_1k)
#define USE_K16 1
#else
#define USE_K16 0
#endif

#if __has_builtin(__builtin_amdgcn_exp2f)
#define EXP2 __builtin_amdgcn_exp2f
#else
#define EXP2 exp2f
#endif

__device__ __forceinline__ floatx4 mfma16(short8 a, short8 b, floatx4 c) {
    return __builtin_amdgcn_mfma_f32_16x16x32_bf16(a, b, c, 0, 0, 0);
}
#if USE_K16
__device__ __forceinline__ floatx4 mfma_k16(short4v a, short4v b, floatx4 c) {
    return __builtin_amdgcn_mfma_f32_16x16x16bf16_1k(a, b, c, 0, 0, 0);
}
#endif

__device__ __forceinline__ short8 ld8(const bf16* p) {
    return *reinterpret_cast<const short8*>(p);
}
__device__ __forceinline__ short4v ld4(const bf16* p) {
    return *reinterpret_cast<const short4v*>(p);
}
__device__ __forceinline__ void st8(bf16* p, short8 v) {
    *reinterpret_cast<short8*>(p) = v;
}
__device__ __forceinline__ unsigned short f2bf(float x) {
    bf16 h = __float2bfloat16(x);
    return reinterpret_cast<unsigned short&>(h);
}

// two fp32 -> packed bf16 pair (round-half-up; inputs positive finite).
// D[15:0]=bf16(a), D[31:16]=bf16(b). 2x v_add + v_perm_b32 (sel in SGPR):
// v_perm combined bytes: 0-3 = S1(=ua), 4-7 = S0(=ub); take {2,3,6,7}.
// PROVEN numerics (9.8e-4); truncation/cvt_pk variants fail threshold.
__device__ __forceinline__ int pack2bf(float a, float b, unsigned sel) {
    const unsigned ua = __float_as_uint(a) + 0x8000u;
    const unsigned ub = __float_as_uint(b) + 0x8000u;
    int r;
    asm("v_perm_b32 %0, %1, %2, %3" : "=v"(r) : "v"(ub), "v"(ua), "s"(sel));
    return r;
}
__device__ __forceinline__ short4v i2s4(int lo, int hi) {
    union { int2 i; short4v s; } u;
    u.i.x = lo; u.i.y = hi;
    return u.s;
}
__device__ __forceinline__ short8 i2s8(int a, int b, int c, int d) {
    union { int4 i; short8 s; } u;
    u.i.x = a; u.i.y = b; u.i.z = c; u.i.w = d;
    return u.s;
}

// async global->LDS, 16 B per lane (global_load_lds_dwordx4).
__device__ __forceinline__ void cp16(const bf16* g, bf16* l) {
    __builtin_amdgcn_global_load_lds(
        (const __attribute__((address_space(1))) void*)g,
        (__attribute__((address_space(3))) void*)l, 16, 0, 0);
}

// ---------------------------------------------------------------------------
// Fused prep: blocks [0,4096) cvt x; [4096,6144) cvt 4 weights;
// [6144,6656) rope cos/sin table. 256 thr, 8 fp32->bf16 per thread.
// ---------------------------------------------------------------------------
__global__ __launch_bounds__(256)
void prep_kernel(const float* __restrict__ x,
                 const float* __restrict__ wq, const float* __restrict__ wk,
                 const float* __restrict__ wv, const float* __restrict__ wo,
                 bf16* __restrict__ xb, bf16* __restrict__ wqb,
                 float2* __restrict__ CS) {
    const int blk = blockIdx.x;
    if (blk < 6144) {
        const float* in;
        bf16* out;
        int i;
        if (blk < 4096) {                 // x: 2^20 groups of 8
            i = blk * 256 + threadIdx.x;
            in = x; out = xb;
        } else {                          // weights: 4 segs of 2^17 groups
            i = (blk - 4096) * 256 + threadIdx.x;
            const int seg = i >> 17;
            const int off = i & 131071;
            in = (seg == 0) ? wq : (seg == 1) ? wk : (seg == 2) ? wv : wo;
            out = wqb + (size_t)i * 8 - (size_t)off * 8;  // seg base
            i = off;
        }
        const float4* p = reinterpret_cast<const float4*>(in) + (size_t)i * 2;
        const float4 a = p[0];
        const float4 b = p[1];
        short8 v;
        v[0] = (short)f2bf(a.x); v[1] = (short)f2bf(a.y);
        v[2] = (short)f2bf(a.z); v[3] = (short)f2bf(a.w);
        v[4] = (short)f2bf(b.x); v[5] = (short)f2bf(b.y);
        v[6] = (short)f2bf(b.z); v[7] = (short)f2bf(b.w);
        *(reinterpret_cast<short8*>(out) + i) = v;
    } else {                              // rope table: 4096*32 entries
        const int i = (blk - 6144) * 256 + threadIdx.x;
        const int t = i >> 5;
        const int j = i & 31;
        const float inv_freq = expf(-(float)j * 0.28782313662425575f); // ln(1e4)/32
        float s, c;
        sincosf((float)t * inv_freq, &s, &c);
        CS[i] = make_float2(c, s);
    }
}

// ---- shared K-loop machinery: 256x128 tile, 8 waves, 3-buffer ring ---------
// A tile 256x32 (2 cp16/thread), B tile 128x32 (1 cp16/thread) = 3 loads/step.
// per step: wait vmcnt(N) (3 main, 3/0 tail), pinned raw barrier, ds_read BUF
// (critical path first), issue loads for k+2 into LB, 16 MFMA. Buffer indices
// compile-time. sched_barrier(0) pins both sides of s_barrier (s_barrier is
// NOT an IR-level memory fence -> R15 cross-wave race without pins).
// srow = tid>>2 (0..127), scol = (tid&3)*8.
#define GEMM_STAGE(Ab, Wb, KK, BUF)                                           \
    do {                                                                      \
        _Pragma("unroll")                                                     \
        for (int j = 0; j < 2; ++j)                                           \
            cp16((Ab) + (size_t)(srow + j * 128) * C_ + (KK) + scol,          \
                 &Als[BUF][(j * 512 + tid) * 8]);                             \
        cp16((Wb) + (size_t)srow * C_ + (KK) + scol, &Bls[BUF][tid * 8]);     \
    } while (0)

#define KSTEP(Ab, Wb, KK, BUF, LB, DOISSUE, VMN)                              \
    do {                                                                      \
        asm volatile("s_waitcnt vmcnt(" VMN ")" ::: "memory");                \
        __builtin_amdgcn_sched_barrier(0);                                    \
        __builtin_amdgcn_s_barrier();                                         \
        __builtin_amdgcn_sched_barrier(0);                                    \
        short8 a[4], b[4];                                                    \
        _Pragma("unroll")                                                     \
        for (int i = 0; i < 4; ++i)                                           \
            a[i] = ld8(&Als[BUF][(wr + i * 16 + lr) * 32 + quad * 8]);        \
        _Pragma("unroll")                                                     \
        for (int j = 0; j < 4; ++j)                                           \
            b[j] = ld8(&Bls[BUF][(wc + j * 16 + lr) * 32 + quad * 8]);        \
        if (DOISSUE) GEMM_STAGE(Ab, Wb, (KK) + 64, LB);                       \
        _Pragma("unroll")                                                     \
        for (int i = 0; i < 4; ++i)                                           \
            _Pragma("unroll")                                                 \
            for (int j = 0; j < 4; ++j)                                       \
                acc[i][j] = mfma16(a[i], b[j], acc[i][j]);                    \
    } while (0)

#define GEMM_MAINLOOP(Ab, Wb)                                                 \
    GEMM_STAGE(Ab, Wb, 0, 0);                                                 \
    GEMM_STAGE(Ab, Wb, 32, 1);                                                \
    for (int kk = 0; kk < 960; kk += 96) {                                    \
        KSTEP(Ab, Wb, kk,      0, 2, 1, "3");                                 \
        KSTEP(Ab, Wb, kk + 32, 1, 0, 1, "3");                                 \
        KSTEP(Ab, Wb, kk + 64, 2, 1, 1, "3");                                 \
    }                                                                         \
    KSTEP(Ab, Wb, 960, 0, 2, 0, "3");                                         \
    KSTEP(Ab, Wb, 992, 1, 0, 0, "0");

// ---------------------------------------------------------------------------
// GEMM: out[m][n] = sum_k A[m][k]*W[n][k]  (A @ W^T).
// 256x128 block tile, 8 waves (each 64x64), BK=32, 3-buffer counted-vmcnt
// pipeline. 1-D grid, XCD-swizzled, n-fastest decomp. ntile = N/128.
// ---------------------------------------------------------------------------
__global__ __launch_bounds__(512, 4)
void gemm128_kernel(const bf16* __restrict__ A, const bf16* __restrict__ W,
                    void* __restrict__ out, int mode, int ntile, int cpx) {
    const int orig = blockIdx.x;
    const int swz  = (orig & 7) * cpx + (orig >> 3);
    const int m0   = (swz / ntile) * 256;
    const int n0   = (swz % ntile) * 128;
    const int tid  = threadIdx.x;
    const int lane = tid & 63;
    const int wave = tid >> 6;            // 0..7
    const int quad = lane >> 4;
    const int lr   = lane & 15;
    const int wr   = (wave >> 1) * 64;    // 0,64,128,192
    const int wc   = (wave & 1) * 64;     // 0,64

    __shared__ __align__(16) bf16 Als[3][256 * 32];
    __shared__ __align__(16) bf16 Bls[3][128 * 32];

    const int srow = tid >> 2;            // 0..127
    const int scol = (tid & 3) * 8;

    floatx4 acc[4][4];
#pragma unroll
    for (int i = 0; i < 4; ++i)
#pragma unroll
        for (int j = 0; j < 4; ++j) acc[i][j] = floatx4{0.f, 0.f, 0.f, 0.f};

    const bf16* Ab = A + (size_t)m0 * C_;
    const bf16* Wb = W + (size_t)n0 * C_;

    GEMM_MAINLOOP(Ab, Wb)

    if (mode == 0) {
        bf16* ob = (bf16*)out;
#pragma unroll
        for (int j = 0; j < 4; ++j) {
            const int col = n0 + wc + j * 16 + lr;
#pragma unroll
            for (int i = 0; i < 4; ++i)
#pragma unroll
                for (int r = 0; r < 4; ++r) {
                    const int m = m0 + wr + i * 16 + quad * 4 + r;
                    ob[(size_t)m * C_ + col] = __float2bfloat16(acc[i][j][r]);
                }
        }
    } else {
        float* of = (float*)out;
#pragma unroll
        for (int j = 0; j < 4; ++j) {
            const int col = n0 + wc + j * 16 + lr;
#pragma unroll
            for (int i = 0; i < 4; ++i)
#pragma unroll
                for (int r = 0; r < 4; ++r) {
                    const int m = m0 + wr + i * 16 + quad * 4 + r;
                    of[(size_t)m * C_ + col] = acc[i][j][r];
                }
        }
    }
}

// ---------------------------------------------------------------------------
// Fused QKV projection GEMM + inline RoPE. W = [wq;wk;wv] contiguous
// (3072 x 1024); out segments Q (flat, roped+scaled), K (flat, roped),
// Vt ([b][h][d][t]) contiguous from Qbase. grid 768 (32 m-tiles x 24
// n-tiles), XCD-swizzled (cpx=96). RoPE pair (d, d+32) lane-local.
// ---------------------------------------------------------------------------
__global__ __launch_bounds__(512, 4)
void gemm_qkv_kernel(const bf16* __restrict__ A, const bf16* __restrict__ W,
                     bf16* __restrict__ Qbase, const float2* __restrict__ CS) {
    const int orig = blockIdx.x;
    const int swz  = (orig & 7) * 96 + (orig >> 3);
    const int m0   = (swz / 24) * 256;
    const int n0g  = (swz % 24) * 128;    // 0..3071
    const int tid  = threadIdx.x;
    const int lane = tid & 63;
    const int wave = tid >> 6;
    const int quad = lane >> 4;
    const int lr   = lane & 15;
    const int wr   = (wave >> 1) * 64;
    const int wc   = (wave & 1) * 64;

    __shared__ __align__(16) bf16 Als[3][256 * 32];
    __shared__ __align__(16) bf16 Bls[3][128 * 32];

    const int srow = tid >> 2;
    const int scol = (tid & 3) * 8;

    floatx4 acc[4][4];
#pragma unroll
    for (int i = 0; i < 4; ++i)
#pragma unroll
        for (int j = 0; j < 4; ++j) acc[i][j] = floatx4{0.f, 0.f, 0.f, 0.f};

    const bf16* Ab = A + (size_t)m0 * C_;
    const bf16* Wb = W + (size_t)n0g * C_;

    GEMM_MAINLOOP(Ab, Wb)

    const int seg = n0g >> 10;           // 0:Q 1:K 2:V
    const int n0  = n0g & 1023;
    if (seg < 2) {
        bf16* ob = Qbase + (size_t)seg * M_ * C_;
        const float scale = (seg == 0) ? QSCALE : 1.0f;
        const int tb = (m0 & 4095) + wr + quad * 4;
#pragma unroll
        for (int j = 0; j < 2; ++j) {             // rotation pair (j, j+2)
            const int col  = n0 + wc + j * 16 + lr;
            const int jcol = j * 16 + lr;          // d in 0..31
#pragma unroll
            for (int i = 0; i < 4; ++i) {
#pragma unroll
                for (int r = 0; r < 4; ++r) {
                    const int t = tb + i * 16 + r;
                    const float2 cs = CS[t * 32 + jcol];
                    const float q1 = acc[i][j][r];
                    const float q2 = acc[i][j + 2][r];
                    const int m = m0 + wr + i * 16 + quad * 4 + r;
                    ob[(size_t)m * C_ + col] =
                        __float2bfloat16((q1 * cs.x - q2 * cs.y) * scale);
                    ob[(size_t)m * C_ + col + 32] =
                        __float2bfloat16((q2 * cs.x + q1 * cs.y) * scale);
                }
            }
        }
    } else {
        unsigned short* ob = (unsigned short*)(Qbase + (size_t)2 * M_ * C_);
        const int b2 = m0 >> 12;
#pragma unroll
        for (int j = 0; j < 4; ++j) {
            const int n = n0 + wc + j * 16 + lr;
            const int h = n >> 6;
            const int d = n & 63;
#pragma unroll
            for (int i = 0; i < 4; ++i) {
                const int t0 = (m0 & 4095) + wr + i * 16 + quad * 4;
                ushort4 v;
                v.x = f2bf(acc[i][j][0]); v.y = f2bf(acc[i][j][1]);
                v.z = f2bf(acc[i][j][2]); v.w = f2bf(acc[i][j][3]);
                size_t idx = ((size_t)((b2 * 16 + h) * 64 + d)) * T_ + t0;
                *reinterpret_cast<ushort4*>(ob + idx) = v;
            }
        }
    }
}

// ---------------------------------------------------------------------------
// Flash attention: 4 waves x 32 q = 128 q rows per block, one (b,h).
// Stage = 64 kv; K and V 64x64 bf16 tiles in XOR-swizzled LDS (no pad):
// 16B chunk c of row r stored at physical chunk c^(r&7). Double-buffered,
// ONE raw barrier per stage (lgkm drain only; vmcnt rides through).
// ---------------------------------------------------------------------------
__global__ __launch_bounds__(256)
void attn_kernel(const bf16* __restrict__ Q, const bf16* __restrict__ K,
                 const bf16* __restrict__ Vt, bf16* __restrict__ AO) {
    const int tid  = threadIdx.x;
    const int lane = tid & 63;
    const int wave = tid >> 6;
    const int quad = lane >> 4;
    const int lr   = lane & 15;
    const int bh   = blockIdx.y;
    const int b    = bh >> 4;
    const int h    = bh & 15;
    const int q0   = blockIdx.x * 128 + wave * 32;   // 32 q rows per wave

    const bf16* Qb = Q + (size_t)b * T_ * C_ + h * 64;
    const bf16* Kb = K + (size_t)b * T_ * C_ + h * 64;
    const bf16* Vb = Vt + (size_t)bh * 64 * T_;

#if USE_K16
    __shared__ __align__(16) bf16 Kls[2][64 * 64];
    __shared__ __align__(16) bf16 Vls[2][64 * 64];

    // staging: thread -> rows {srow, srow+32}, logical chunk sc (16B)
    const int srow  = tid >> 3;              // 0..31
    const int sc    = tid & 7;
    const int sphys = (sc ^ (srow & 7)) * 8; // physical chunk offset (bf16)
    const int soff0 = srow * 64 + sphys;
    const int soff1 = (srow + 32) * 64 + sphys;  // (srow+32)&7 == srow&7

    // v_perm selector for pack2bf, kept in SGPR (hoisted out of the loop)
    const unsigned psel = 0x07060302u;
    // constants: zero C operand for QK, bf16 ones for row-sum MFMA
    const floatx4 FZ = {0.f, 0.f, 0.f, 0.f};
    const int one2 = 0x3F803F80;
    const short8 VONE = i2s8(one2, one2, one2, one2);

    short8 aq[2][2];
#pragma unroll
    for (int t = 0; t < 2; ++t) {
        aq[t][0] = ld8(Qb + (size_t)(q0 + t * 16 + lr) * C_ + quad * 8);
        aq[t][1] = ld8(Qb + (size_t)(q0 + t * 16 + lr) * C_ + 32 + quad * 8);
    }

    floatx4 O[2][4];
#pragma unroll
    for (int t = 0; t < 2; ++t)
#pragma unroll
        for (int dt = 0; dt < 4; ++dt) O[t][dt] = floatx4{0.f, 0.f, 0.f, 0.f};
    floatx4 Osum[2] = {{0.f, 0.f, 0.f, 0.f}, {0.f, 0.f, 0.f, 0.f}};

    // hoisted per-lane swizzled LDS element offsets (loop-invariant)
    const int lr7    = lr & 7;
    const int kchunk = (quad ^ lr7) * 8;     // K: logical chunk = quad
    const int vsub   = (quad & 1) * 4;
    const int vbq    = quad >> 1;
    const int kel0   = lr * 64 + kchunk;     // + kk*1024 imm
    const int kel1   = kel0 ^ 32;
    int velk[4];                             // constant-indexed only
#pragma unroll
    for (int kk = 0; kk < 4; ++kk)
        velk[kk] = lr * 64 + (((2 * kk + vbq) ^ lr7) * 8) + vsub;  // + dt*1024 imm

    short8 kr0, kr1, vr0, vr1;
#define LOAD_STAGE(kv0)                                              \
    do {                                                             \
        kr0 = ld8(Kb + (size_t)((kv0) + srow) * C_ + sc * 8);        \
        kr1 = ld8(Kb + (size_t)((kv0) + srow + 32) * C_ + sc * 8);   \
        vr0 = ld8(Vb + (size_t)srow * T_ + (kv0) + sc * 8);          \
        vr1 = ld8(Vb + (size_t)(srow + 32) * T_ + (kv0) + sc * 8);   \
    } while (0)
#define STORE_STAGE(p)                                               \
    do {                                                             \
        st8(&Kls[p][soff0], kr0);                                    \
        st8(&Kls[p][soff1], kr1);                                    \
        st8(&Vls[p][soff0], vr0);                                    \
        st8(&Vls[p][soff1], vr1);                                    \
    } while (0)

// raw barrier: drain LDS ops only; global prefetch stays in flight (vmcnt)
#define BAR()                                                        \
    do {                                                             \
        asm volatile("s_waitcnt lgkmcnt(0)" ::: "memory");           \
        __builtin_amdgcn_s_barrier();                                \
    } while (0)

// compute one 64-kv stage from compile-time buffer P
#define COMPUTE(P)                                                            \
    do {                                                                      \
        const bf16* Ks = Kls[P];                                              \
        const bf16* Vs = Vls[P];                                              \
        int prlo[2][4], prhi[2][4];                                           \
        _Pragma("unroll")                                                     \
        for (int kk = 0; kk < 4; ++kk) {                                      \
            const short8 kf0 = ld8(Ks + kk * 1024 + kel0);                    \
            const short8 kf1 = ld8(Ks + kk * 1024 + kel1);                    \
            floatx4 s0 = mfma16(kf0, aq[0][0], FZ);                           \
            s0 = mfma16(kf1, aq[0][1], s0);                                   \
            floatx4 s1 = mfma16(kf0, aq[1][0], FZ);                           \
            s1 = mfma16(kf1, aq[1][1], s1);                                   \
            const float e0 = EXP2(s0[0]), e1 = EXP2(s0[1]);                   \
            const float e2 = EXP2(s0[2]), e3 = EXP2(s0[3]);                   \
            prlo[0][kk] = pack2bf(e0, e1, psel);                              \
            prhi[0][kk] = pack2bf(e2, e3, psel);                              \
            const float f0 = EXP2(s1[0]), f1 = EXP2(s1[1]);                   \
            const float f2 = EXP2(s1[2]), f3 = EXP2(s1[3]);                   \
            prlo[1][kk] = pack2bf(f0, f1, psel);                              \
            prhi[1][kk] = pack2bf(f2, f3, psel);                              \
        }                                                                     \
        /* row sums: k-permutation-invariant -> feed packed P into 16x16x32 */\
        Osum[0] = mfma16(i2s8(prlo[0][0], prhi[0][0], prlo[0][1], prhi[0][1]),\
                         VONE, Osum[0]);                                      \
        Osum[0] = mfma16(i2s8(prlo[0][2], prhi[0][2], prlo[0][3], prhi[0][3]),\
                         VONE, Osum[0]);                                      \
        Osum[1] = mfma16(i2s8(prlo[1][0], prhi[1][0], prlo[1][1], prhi[1][1]),\
                         VONE, Osum[1]);                                      \
        Osum[1] = mfma16(i2s8(prlo[1][2], prhi[1][2], prlo[1][3], prhi[1][3]),\
                         VONE, Osum[1]);                                      \
        __builtin_amdgcn_s_setprio(1);                                        \
        _Pragma("unroll")                                                     \
        for (int dt = 0; dt < 4; ++dt) {                                      \
            _Pragma("unroll")                                                 \
            for (int kk = 0; kk < 4; ++kk) {                                  \
                const short4v vf = ld4(Vs + dt * 1024 + velk[kk]);            \
                O[0][dt] = mfma_k16(i2s4(prlo[0][kk], prhi[0][kk]), vf, O[0][dt]); \
                O[1][dt] = mfma_k16(i2s4(prlo[1][kk], prhi[1][kk]), vf, O[1][dt]); \
            }                                                                 \
        }                                                                     \
        __builtin_amdgcn_s_setprio(0);                                        \
    } while (0)

    LOAD_STAGE(0);
    STORE_STAGE(0);
    LOAD_STAGE(64);
    BAR();

    constexpr int NS = T_ / 64;
    for (int s = 0; s < NS; s += 2) {
        // even stage: compute buffer 0
        if (s + 1 < NS) STORE_STAGE(1);          // buffer last read at s-1
        if (s + 2 < NS) LOAD_STAGE((s + 2) * 64);
        COMPUTE(0);
        BAR();
        // odd stage: compute buffer 1
        if (s + 2 < NS) STORE_STAGE(0);
        if (s + 3 < NS) LOAD_STAGE((s + 3) * 64);
        COMPUTE(1);
        BAR();
    }

    // epilogue: lane (quad,lr) holds Osum[t][r] for q-row = quad*4+r directly
#pragma unroll
    for (int t = 0; t < 2; ++t) {
#pragma unroll
        for (int r = 0; r < 4; ++r) {
            const float inv = 1.0f / fmaxf(Osum[t][r], 1e-30f);
            const size_t row =
                (size_t)(b * T_ + q0 + t * 16 + quad * 4 + r) * C_ + h * 64;
            AO[row + 0  + lr] = __float2bfloat16(O[t][0][r] * inv);
            AO[row + 16 + lr] = __float2bfloat16(O[t][1][r] * inv);
            AO[row + 32 + lr] = __float2bfloat16(O[t][2][r] * inv);
            AO[row + 48 + lr] = __float2bfloat16(O[t][3][r] * inv);
        }
    }
#undef LOAD_STAGE
#undef STORE_STAGE
#undef COMPUTE
#undef BAR
#else
    // Fallback (no 16x16x16 builtin): LDS P round-trip path, exp2-based.
    __shared__ __align__(16) unsigned short Pbuf[4][512];
    unsigned short* Pw = Pbuf[wave];
    for (int half = 0; half < 2; ++half) {
        const int qh = q0 + half * 16;
        const short8 aq0 = ld8(Qb + (size_t)(qh + lr) * C_ + quad * 8);
        const short8 aq1 = ld8(Qb + (size_t)(qh + lr) * C_ + 32 + quad * 8);
        floatx4 O0 = {0,0,0,0}, O1 = {0,0,0,0}, O2 = {0,0,0,0}, O3 = {0,0,0,0};
        float lrun[4] = {0.f, 0.f, 0.f, 0.f};
        for (int kv = 0; kv < T_; kv += 32) {
            floatx4 S0 = {0,0,0,0}, S1 = {0,0,0,0};
            const bf16* k0 = Kb + (size_t)(kv + lr) * C_ + quad * 8;
            const bf16* k1 = Kb + (size_t)(kv + 16 + lr) * C_ + quad * 8;
            S0 = mfma16(aq0, ld8(k0), S0);
            S0 = mfma16(aq1, ld8(k0 + 32), S0);
            S1 = mfma16(aq0, ld8(k1), S1);
            S1 = mfma16(aq1, ld8(k1 + 32), S1);
#pragma unroll
            for (int r = 0; r < 4; ++r) {
                const float e0 = exp2f(S0[r]);
                const float e1 = exp2f(S1[r]);
                lrun[r] += e0 + e1;
                const int row = quad * 4 + r;
                Pw[row * 32 + lr]      = f2bf(e0);
                Pw[row * 32 + 16 + lr] = f2bf(e1);
            }
            __syncthreads();
            const short8 ap = *reinterpret_cast<const short8*>(Pw + lr * 32 + quad * 8);
            O0 = mfma16(ap, ld8(Vb + (size_t)(lr)      * T_ + kv + quad * 8), O0);
            O1 = mfma16(ap, ld8(Vb + (size_t)(16 + lr) * T_ + kv + quad * 8), O1);
            O2 = mfma16(ap, ld8(Vb + (size_t)(32 + lr) * T_ + kv + quad * 8), O2);
            O3 = mfma16(ap, ld8(Vb + (size_t)(48 + lr) * T_ + kv + quad * 8), O3);
            __syncthreads();
        }
#pragma unroll
        for (int r = 0; r < 4; ++r) {
            float l = lrun[r];
            l += __shfl_xor(l, 1); l += __shfl_xor(l, 2);
            l += __shfl_xor(l, 4); l += __shfl_xor(l, 8);
            const float inv = 1.0f / fmaxf(l, 1e-30f);
            const size_t row = (size_t)(b * T_ + qh + quad * 4 + r) * C_ + h * 64;
            AO[row + 0  + lr] = __float2bfloat16(O0[r] * inv);
            AO[row + 16 + lr] = __float2bfloat16(O1[r] * inv);
            AO[row + 32 + lr] = __float2bfloat16(O2[r] * inv);
            AO[row + 48 + lr] = __float2bfloat16(O3[r] * inv);
        }
    }
#endif
}

// ---------------------------------------------------------------------------
extern "C" void kernel_launch(void* const* d_in, const int* in_sizes, int n_in,
                              void* d_out, int out_size, void* d_ws, size_t ws_size,
                              hipStream_t stream) {
    const float* x  = (const float*)d_in[0];
    const float* wq = (const float*)d_in[1];
    const float* wk = (const float*)d_in[2];
    const float* wv = (const float*)d_in[3];
    const float* wo = (const float*)d_in[4];
    float* out = (float*)d_out;

    bf16* xb  = (bf16*)d_ws;
    bf16* wqb = xb  + (size_t)M_ * C_;
    bf16* wkb = wqb + (size_t)C_ * C_;
    bf16* wvb = wkb + (size_t)C_ * C_;
    bf16* wob = wvb + (size_t)C_ * C_;
    bf16* Q   = wob + (size_t)C_ * C_;
    bf16* K   = Q   + (size_t)M_ * C_;
    bf16* Vt  = K   + (size_t)M_ * C_;
    float2* CS = (float2*)(Vt + (size_t)M_ * C_);   // [4096][32] cos/sin, 1 MB
    bf16* AO  = xb;   // aliases xb; x dead after V GEMM

    // fused prep: x cvt (4096 blk) + weight cvt (2048 blk) + rope table (512)
    prep_kernel<<<6656, 256, 0, stream>>>(x, wq, wk, wv, wo, xb, wqb, CS);

    // fused QKV projection + RoPE: W = [wq;wk;wv] contiguous,
    // outs Q (roped+scaled), K (roped), Vt contiguous. XCD-swizzled.
    // grid 768 = 32 m-tiles (256) x 24 n-tiles (128), cpx=96.
    gemm_qkv_kernel<<<768, 512, 0, stream>>>(xb, wqb, Q, CS);

    attn_kernel<<<dim3(T_ / 128, 32), 256, 0, stream>>>(Q, K, Vt, AO);

    // final projection, fp32 out. grid 256 = 32 m-tiles x 8 n-tiles, cpx=32.
    gemm128_kernel<<<256, 512, 0, stream>>>(AO, wob, out, 2, 8, 32);
}